// Round 4
// baseline (184.730 us; speedup 1.0000x reference)
//
#include <hip/hip_runtime.h>

#define IMG_H 512
#define IMG_W 512
#define HW (IMG_H * IMG_W)
#define NB 32
#define STRIPS 32           // blocks per image; block = 4 waves x 4 rows = 16 rows
#define RPW 4               // rows per wave

// Workspace layout (doubles first, then histogram):
//   acc[0..31]    lap_sum     acc[32..63]  lap_sumsq
//   acc[64..95]   depth_n     acc[96..127] depth_sum   acc[128..159] depth_sumsq
//   hist: 32*256 uint at byte offset 160*8
#define ACC_DOUBLES 160
#define WS_BYTES (ACC_DOUBLES * 8 + NB * 256 * 4)

struct Row6 { float4 a0, a1, b0, b1, c0, c1; };

__device__ inline Row6 load_row(const float* __restrict__ rp, int r, int c0) {
    Row6 x;
    if ((unsigned)r < IMG_H) {          // wave-uniform branch
        const size_t o = (size_t)r * IMG_W + c0;
        x.a0 = *(const float4*)(rp + o);
        x.a1 = *(const float4*)(rp + o + 4);
        x.b0 = *(const float4*)(rp + HW + o);
        x.b1 = *(const float4*)(rp + HW + o + 4);
        x.c0 = *(const float4*)(rp + 2 * HW + o);
        x.c1 = *(const float4*)(rp + 2 * HW + o + 4);
    } else {
        const float4 z = {0.f, 0.f, 0.f, 0.f};
        x.a0 = x.a1 = x.b0 = x.b1 = x.c0 = x.c1 = z;
    }
    return x;
}

__device__ inline void to_gray(const Row6& x, float g[8]) {
    g[0] = 0.299f * x.a0.x + 0.587f * x.b0.x + 0.114f * x.c0.x;
    g[1] = 0.299f * x.a0.y + 0.587f * x.b0.y + 0.114f * x.c0.y;
    g[2] = 0.299f * x.a0.z + 0.587f * x.b0.z + 0.114f * x.c0.z;
    g[3] = 0.299f * x.a0.w + 0.587f * x.b0.w + 0.114f * x.c0.w;
    g[4] = 0.299f * x.a1.x + 0.587f * x.b1.x + 0.114f * x.c1.x;
    g[5] = 0.299f * x.a1.y + 0.587f * x.b1.y + 0.114f * x.c1.y;
    g[6] = 0.299f * x.a1.z + 0.587f * x.b1.z + 0.114f * x.c1.z;
    g[7] = 0.299f * x.a1.w + 0.587f * x.b1.w + 0.114f * x.c1.w;
}

// Barrier-free streaming: wave w of block (s,b) owns rows [s*16 + w*4, +4),
// lane owns 8 consecutive columns. prev/cur/next gray rows live in registers;
// horizontal neighbors via shuffle. Depth chunk interleaved into the same loop.
// Grid 32x32 = 1024 blocks = 4 blocks/CU = 4 waves/SIMD for latency hiding.
__global__ __launch_bounds__(256, 4) void fused_kernel(
    const float* __restrict__ rgb, const float* __restrict__ depth,
    double* __restrict__ acc, unsigned int* __restrict__ hist)
{
    __shared__ unsigned int lh[4][256];
    __shared__ double red[4][5];

    const int t = threadIdx.x;
    const int b = blockIdx.y;
    const int s = blockIdx.x;
    const int lane = t & 63;
    const int w = t >> 6;

    #pragma unroll
    for (int i = 0; i < 4; ++i) lh[i][t & 255] = 0u;
    __syncthreads();

    const float* rp = rgb + (size_t)b * 3 * HW;
    const int rb = s * 16 + w * RPW;      // first owned row
    const int c0 = lane * 8;              // first owned column

    const float4* dp = (const float4*)(depth + (size_t)b * HW + (size_t)s * (HW / STRIPS));

    float gp[8], gc[8], gn[8];
    Row6 st0 = load_row(rp, rb - 1, c0);
    Row6 st1 = load_row(rp, rb, c0);
    to_gray(st0, gp);
    to_gray(st1, gc);

    float s1 = 0.f, s2 = 0.f;
    float dnf = 0.f, dsf = 0.f, dqf = 0.f;

    #pragma unroll
    for (int r = 0; r < RPW; ++r) {
        const Row6 nx = load_row(rp, rb + r + 1, c0);
        const float4 d0 = dp[(2 * r) * 256 + t];
        const float4 d1 = dp[(2 * r + 1) * 256 + t];
        to_gray(nx, gn);

        float lf = __shfl_up(gc[7], 1, 64);
        if (lane == 0) lf = 0.f;
        float rt = __shfl_down(gc[0], 1, 64);
        if (lane == 63) rt = 0.f;

        #pragma unroll
        for (int j = 0; j < 8; ++j) {
            const float left  = (j == 0) ? lf : gc[j - 1];
            const float right = (j == 7) ? rt : gc[j + 1];
            const float lap = gp[j] + gn[j] + left + right - 4.f * gc[j];
            s1 += lap;
            s2 += lap * lap;
            atomicAdd(&lh[w][(int)fminf(fmaxf(gc[j] * 255.f, 0.f), 255.f)], 1u);
        }

        if (d0.x > 0.f) { dnf += 1.f; dsf += d0.x; dqf += d0.x * d0.x; }
        if (d0.y > 0.f) { dnf += 1.f; dsf += d0.y; dqf += d0.y * d0.y; }
        if (d0.z > 0.f) { dnf += 1.f; dsf += d0.z; dqf += d0.z * d0.z; }
        if (d0.w > 0.f) { dnf += 1.f; dsf += d0.w; dqf += d0.w * d0.w; }
        if (d1.x > 0.f) { dnf += 1.f; dsf += d1.x; dqf += d1.x * d1.x; }
        if (d1.y > 0.f) { dnf += 1.f; dsf += d1.y; dqf += d1.y * d1.y; }
        if (d1.z > 0.f) { dnf += 1.f; dsf += d1.z; dqf += d1.z * d1.z; }
        if (d1.w > 0.f) { dnf += 1.f; dsf += d1.w; dqf += d1.w * d1.w; }

        #pragma unroll
        for (int j = 0; j < 8; ++j) { gp[j] = gc[j]; gc[j] = gn[j]; }
    }

    // block reduction of the 5 scalars
    double z0 = (double)s1, z1 = (double)s2, z2 = (double)dnf, z3 = (double)dsf, z4 = (double)dqf;
    for (int off = 32; off > 0; off >>= 1) {
        z0 += __shfl_down(z0, off, 64);
        z1 += __shfl_down(z1, off, 64);
        z2 += __shfl_down(z2, off, 64);
        z3 += __shfl_down(z3, off, 64);
        z4 += __shfl_down(z4, off, 64);
    }
    if (lane == 0) {
        red[w][0] = z0; red[w][1] = z1; red[w][2] = z2; red[w][3] = z3; red[w][4] = z4;
    }
    __syncthreads();   // covers lh writes and red[] writes

    const unsigned int hsum = lh[0][t] + lh[1][t] + lh[2][t] + lh[3][t];
    atomicAdd(&hist[b * 256 + t], hsum);
    if (t < 5) {
        const double v = red[0][t] + red[1][t] + red[2][t] + red[3][t];
        atomicAdd(&acc[t * 32 + b], v);
    }
}

__global__ __launch_bounds__(256) void final_kernel(
    const double* __restrict__ acc,
    const unsigned int* __restrict__ hist,
    float* __restrict__ out)
{
    __shared__ float part[256];
    const int t = threadIdx.x;
    const int b = t >> 3;        // 0..31
    const int sl = t & 7;        // 8 slices of 32 bins
    float e = 0.f;
    #pragma unroll
    for (int i = 0; i < 32; ++i) {
        const float p = (float)hist[b * 256 + sl * 32 + i] * (1.0f / (float)HW);
        e += p * log2f(p + 1e-4f);
    }
    part[t] = e;
    __syncthreads();

    if (t < NB) {
        float es = 0.f;
        #pragma unroll
        for (int i = 0; i < 8; ++i) es += part[t * 8 + i];
        const double entropy = -(double)es;
        const double N = (double)HW;

        const double ls = acc[t], lq = acc[32 + t];
        const double lvar = (lq - ls * ls / N) / (N - 1.0);
        const double clarity = lvar / (1000.0 + 1e-4);
        const double uniformity = 1.0 / (entropy + 1e-4);
        const double rgb_conf = 0.5 * (clarity + uniformity);

        const double n = acc[64 + t], sdep = acc[96 + t], q = acc[128 + t];
        const double mean = sdep / fmax(n, 1.0);
        const double sq = q - 2.0 * mean * sdep + mean * mean * n;
        const double var = sq / fmax(n - 1.0, 1.0);
        const double stdd = sqrt(fmax(var, 0.0));
        const double noise = (n > 0.0) ? stdd : 1.0;
        const double density = n / N;
        const double depth_conf = 0.5 * (density / (10000.0 + 1e-4) + 1.0 / (noise + 1e-4));

        const double denom = rgb_conf + depth_conf + 1e-4;
        out[t]      = (float)(rgb_conf / denom);
        out[NB + t] = (float)(depth_conf / denom);
    }
}

extern "C" void kernel_launch(void* const* d_in, const int* in_sizes, int n_in,
                              void* d_out, int out_size, void* d_ws, size_t ws_size,
                              hipStream_t stream) {
    const float* rgb   = (const float*)d_in[0];
    const float* depth = (const float*)d_in[1];
    float* out = (float*)d_out;

    double* acc = (double*)d_ws;
    unsigned int* hist = (unsigned int*)((char*)d_ws + ACC_DOUBLES * 8);

    hipMemsetAsync(d_ws, 0, WS_BYTES, stream);

    fused_kernel<<<dim3(STRIPS, NB), 256, 0, stream>>>(rgb, depth, acc, hist);
    final_kernel<<<1, 256, 0, stream>>>(acc, hist, out);
}

// Round 5
// 178.773 us; speedup vs baseline: 1.0333x; 1.0333x over previous
//
#include <hip/hip_runtime.h>

#define IMG_H 512
#define IMG_W 512
#define HW (IMG_H * IMG_W)
#define NB 32
#define STRIPS 16           // blocks per image; block = 4 waves x 8 rows = 32 rows
#define RPW 8               // rows per wave

// Workspace layout (doubles first, then histogram):
//   acc[0..31]    lap_sum     acc[32..63]  lap_sumsq
//   acc[64..95]   depth_n     acc[96..127] depth_sum   acc[128..159] depth_sumsq
//   hist: 32*256 uint at byte offset 160*8
#define ACC_DOUBLES 160
#define WS_BYTES (ACC_DOUBLES * 8 + NB * 256 * 4)

struct Row6 { float4 a0, a1, b0, b1, c0, c1; };

__device__ inline Row6 load_row(const float* __restrict__ rp, int r, int c0) {
    Row6 x;
    if ((unsigned)r < IMG_H) {          // wave-uniform branch
        const size_t o = (size_t)r * IMG_W + c0;
        x.a0 = *(const float4*)(rp + o);
        x.a1 = *(const float4*)(rp + o + 4);
        x.b0 = *(const float4*)(rp + HW + o);
        x.b1 = *(const float4*)(rp + HW + o + 4);
        x.c0 = *(const float4*)(rp + 2 * HW + o);
        x.c1 = *(const float4*)(rp + 2 * HW + o + 4);
    } else {
        const float4 z = {0.f, 0.f, 0.f, 0.f};
        x.a0 = x.a1 = x.b0 = x.b1 = x.c0 = x.c1 = z;
    }
    return x;
}

__device__ inline void to_gray(const Row6& x, float g[8]) {
    g[0] = 0.299f * x.a0.x + 0.587f * x.b0.x + 0.114f * x.c0.x;
    g[1] = 0.299f * x.a0.y + 0.587f * x.b0.y + 0.114f * x.c0.y;
    g[2] = 0.299f * x.a0.z + 0.587f * x.b0.z + 0.114f * x.c0.z;
    g[3] = 0.299f * x.a0.w + 0.587f * x.b0.w + 0.114f * x.c0.w;
    g[4] = 0.299f * x.a1.x + 0.587f * x.b1.x + 0.114f * x.c1.x;
    g[5] = 0.299f * x.a1.y + 0.587f * x.b1.y + 0.114f * x.c1.y;
    g[6] = 0.299f * x.a1.z + 0.587f * x.b1.z + 0.114f * x.c1.z;
    g[7] = 0.299f * x.a1.w + 0.587f * x.b1.w + 0.114f * x.c1.w;
}

// Barrier-free streaming with explicit 3-deep prefetch ring: wave w of block
// (s,b) owns rows [s*32 + w*8, +8), lane owns 8 consecutive columns.
// buf[] keeps ~2.5 row-batches of loads in flight at all times.
// __launch_bounds__(256,2): 2 waves/EU -> 256-VGPR budget, no clamping to 64.
__global__ __launch_bounds__(256, 2) void fused_kernel(
    const float* __restrict__ rgb, const float* __restrict__ depth,
    double* __restrict__ acc, unsigned int* __restrict__ hist)
{
    __shared__ unsigned int lh[4][256];
    __shared__ double red[4][5];

    const int t = threadIdx.x;
    const int b = blockIdx.y;
    const int s = blockIdx.x;
    const int lane = t & 63;
    const int w = t >> 6;

    #pragma unroll
    for (int i = 0; i < 4; ++i) lh[i][t & 255] = 0u;
    __syncthreads();

    const float* rp = rgb + (size_t)b * 3 * HW;
    const int rb = s * 32 + w * RPW;      // first owned row
    const int c0 = lane * 8;              // first owned column

    const float4* dp = (const float4*)(depth + (size_t)b * HW + (size_t)s * (HW / STRIPS));

    // ---- prologue: 5 row-loads + 6 depth loads issued before any consumption ----
    Row6 r0 = load_row(rp, rb - 1, c0);
    Row6 r1 = load_row(rp, rb, c0);
    Row6 buf[3];
    float4 dv[3][2];
    buf[0] = load_row(rp, rb + 1, c0); dv[0][0] = dp[0 * 256 + t]; dv[0][1] = dp[1 * 256 + t];
    buf[1] = load_row(rp, rb + 2, c0); dv[1][0] = dp[2 * 256 + t]; dv[1][1] = dp[3 * 256 + t];
    buf[2] = load_row(rp, rb + 3, c0); dv[2][0] = dp[4 * 256 + t]; dv[2][1] = dp[5 * 256 + t];

    float gp[8], gc[8], gn[8];
    to_gray(r0, gp);
    to_gray(r1, gc);

    float s1 = 0.f, s2 = 0.f;
    float dnf = 0.f, dsf = 0.f, dqf = 0.f;

    #pragma unroll
    for (int r = 0; r < RPW; ++r) {
        const int bi = r % 3;
        to_gray(buf[bi], gn);
        const float4 d0 = dv[bi][0];
        const float4 d1 = dv[bi][1];

        // refill the consumed slot (row rb+r+4, depth pairs 2r+6, 2r+7)
        if (r < RPW - 3) {
            buf[bi] = load_row(rp, rb + r + 4, c0);
            dv[bi][0] = dp[(2 * r + 6) * 256 + t];
            dv[bi][1] = dp[(2 * r + 7) * 256 + t];
        }

        float lf = __shfl_up(gc[7], 1, 64);
        if (lane == 0) lf = 0.f;
        float rt = __shfl_down(gc[0], 1, 64);
        if (lane == 63) rt = 0.f;

        #pragma unroll
        for (int j = 0; j < 8; ++j) {
            const float left  = (j == 0) ? lf : gc[j - 1];
            const float right = (j == 7) ? rt : gc[j + 1];
            const float lap = gp[j] + gn[j] + left + right - 4.f * gc[j];
            s1 += lap;
            s2 += lap * lap;
            atomicAdd(&lh[w][(int)fminf(fmaxf(gc[j] * 255.f, 0.f), 255.f)], 1u);
        }

        if (d0.x > 0.f) { dnf += 1.f; dsf += d0.x; dqf += d0.x * d0.x; }
        if (d0.y > 0.f) { dnf += 1.f; dsf += d0.y; dqf += d0.y * d0.y; }
        if (d0.z > 0.f) { dnf += 1.f; dsf += d0.z; dqf += d0.z * d0.z; }
        if (d0.w > 0.f) { dnf += 1.f; dsf += d0.w; dqf += d0.w * d0.w; }
        if (d1.x > 0.f) { dnf += 1.f; dsf += d1.x; dqf += d1.x * d1.x; }
        if (d1.y > 0.f) { dnf += 1.f; dsf += d1.y; dqf += d1.y * d1.y; }
        if (d1.z > 0.f) { dnf += 1.f; dsf += d1.z; dqf += d1.z * d1.z; }
        if (d1.w > 0.f) { dnf += 1.f; dsf += d1.w; dqf += d1.w * d1.w; }

        #pragma unroll
        for (int j = 0; j < 8; ++j) { gp[j] = gc[j]; gc[j] = gn[j]; }
    }

    // block reduction of the 5 scalars
    double z0 = (double)s1, z1 = (double)s2, z2 = (double)dnf, z3 = (double)dsf, z4 = (double)dqf;
    for (int off = 32; off > 0; off >>= 1) {
        z0 += __shfl_down(z0, off, 64);
        z1 += __shfl_down(z1, off, 64);
        z2 += __shfl_down(z2, off, 64);
        z3 += __shfl_down(z3, off, 64);
        z4 += __shfl_down(z4, off, 64);
    }
    if (lane == 0) {
        red[w][0] = z0; red[w][1] = z1; red[w][2] = z2; red[w][3] = z3; red[w][4] = z4;
    }
    __syncthreads();   // covers lh writes and red[] writes

    const unsigned int hsum = lh[0][t] + lh[1][t] + lh[2][t] + lh[3][t];
    atomicAdd(&hist[b * 256 + t], hsum);
    if (t < 5) {
        const double v = red[0][t] + red[1][t] + red[2][t] + red[3][t];
        atomicAdd(&acc[t * 32 + b], v);
    }
}

__global__ __launch_bounds__(256) void final_kernel(
    const double* __restrict__ acc,
    const unsigned int* __restrict__ hist,
    float* __restrict__ out)
{
    __shared__ float part[256];
    const int t = threadIdx.x;
    const int b = t >> 3;        // 0..31
    const int sl = t & 7;        // 8 slices of 32 bins
    float e = 0.f;
    #pragma unroll
    for (int i = 0; i < 32; ++i) {
        const float p = (float)hist[b * 256 + sl * 32 + i] * (1.0f / (float)HW);
        e += p * log2f(p + 1e-4f);
    }
    part[t] = e;
    __syncthreads();

    if (t < NB) {
        float es = 0.f;
        #pragma unroll
        for (int i = 0; i < 8; ++i) es += part[t * 8 + i];
        const double entropy = -(double)es;
        const double N = (double)HW;

        const double ls = acc[t], lq = acc[32 + t];
        const double lvar = (lq - ls * ls / N) / (N - 1.0);
        const double clarity = lvar / (1000.0 + 1e-4);
        const double uniformity = 1.0 / (entropy + 1e-4);
        const double rgb_conf = 0.5 * (clarity + uniformity);

        const double n = acc[64 + t], sdep = acc[96 + t], q = acc[128 + t];
        const double mean = sdep / fmax(n, 1.0);
        const double sq = q - 2.0 * mean * sdep + mean * mean * n;
        const double var = sq / fmax(n - 1.0, 1.0);
        const double stdd = sqrt(fmax(var, 0.0));
        const double noise = (n > 0.0) ? stdd : 1.0;
        const double density = n / N;
        const double depth_conf = 0.5 * (density / (10000.0 + 1e-4) + 1.0 / (noise + 1e-4));

        const double denom = rgb_conf + depth_conf + 1e-4;
        out[t]      = (float)(rgb_conf / denom);
        out[NB + t] = (float)(depth_conf / denom);
    }
}

extern "C" void kernel_launch(void* const* d_in, const int* in_sizes, int n_in,
                              void* d_out, int out_size, void* d_ws, size_t ws_size,
                              hipStream_t stream) {
    const float* rgb   = (const float*)d_in[0];
    const float* depth = (const float*)d_in[1];
    float* out = (float*)d_out;

    double* acc = (double*)d_ws;
    unsigned int* hist = (unsigned int*)((char*)d_ws + ACC_DOUBLES * 8);

    hipMemsetAsync(d_ws, 0, WS_BYTES, stream);

    fused_kernel<<<dim3(STRIPS, NB), 256, 0, stream>>>(rgb, depth, acc, hist);
    final_kernel<<<1, 256, 0, stream>>>(acc, hist, out);
}